// Round 9
// baseline (151.883 us; speedup 1.0000x reference)
//
#include <hip/hip_runtime.h>
#include <hip/hip_bf16.h>
#include <cstdint>

// Problem constants (features: [512, 16, 512] fp32 -> N=8192 rows, D=512)
#define N_TOT 8192
#define DDIM  512
#define DBYTES 512                     // bytes per row in fp8
#define NBLK  64                       // 8192 / 128 tile blocks per dim
#define NCHUNK 544                     // sum over bi of ceil((bi+1)/4)
constexpr float INV_T = 1.0f / 0.07f;

typedef uint8_t u8;
typedef __attribute__((ext_vector_type(8))) int i32x8_t;
typedef __attribute__((ext_vector_type(4))) float f32x4_t;

// ---- helpers ---------------------------------------------------------------

// async 16B global->LDS (global_load_lds_dwordx4). LDS dst is wave-uniform
// base + lane*16 (lane-contiguous) -- swizzle is applied to the GLOBAL src.
__device__ __forceinline__ void load16_to_lds(const void* g, void* l) {
  __builtin_amdgcn_global_load_lds(
      (const __attribute__((address_space(1))) unsigned int*)g,
      (__attribute__((address_space(3))) unsigned int*)l, 16, 0, 0);
}

// B-fragment (4x 16x128 f8 frags) straight from global into registers.
__device__ __forceinline__ void loadB(const u8* __restrict__ Xn, int colBase,
                                      int wn, int l15, int quad, int kk,
                                      i32x8_t b[4]) {
#pragma unroll
  for (int ni = 0; ni < 4; ni++) {
    const u8* p = Xn + (size_t)(colBase + wn * 64 + ni * 16 + l15) * DBYTES +
                  kk * 128 + quad * 32;
    int4 lo = *(const int4*)p;
    int4 hi = *(const int4*)(p + 16);
    b[ni] = (i32x8_t){lo.x, lo.y, lo.z, lo.w, hi.x, hi.y, hi.z, hi.w};
  }
}

// ---- kernel 1: row-normalize fp32 -> fp8 e4m3 (+ zero tsum and out) --------
__global__ __launch_bounds__(256) void normalize_kernel(const float* __restrict__ X,
                                                        u8* __restrict__ Xn,
                                                        float* __restrict__ tsum,
                                                        float* __restrict__ out) {
  if (blockIdx.x < 32) tsum[blockIdx.x * 256 + threadIdx.x] = 0.0f;
  if (blockIdx.x == 32 && threadIdx.x == 0) out[0] = 0.0f;
  const int lane = threadIdx.x & 63;
  const int row  = blockIdx.x * 4 + (threadIdx.x >> 6);
  const float4* xr = (const float4*)(X + (size_t)row * DDIM);
  float4 v0 = xr[lane];
  float4 v1 = xr[lane + 64];
  float s = v0.x * v0.x + v0.y * v0.y + v0.z * v0.z + v0.w * v0.w
          + v1.x * v1.x + v1.y * v1.y + v1.z * v1.z + v1.w * v1.w;
#pragma unroll
  for (int m = 1; m < 64; m <<= 1) s += __shfl_xor(s, m);
  const float scale = 1.0f / fmaxf(sqrtf(s), 1e-8f);
  int w0 = __builtin_amdgcn_cvt_pk_fp8_f32(v0.x * scale, v0.y * scale, 0, 0);
  w0     = __builtin_amdgcn_cvt_pk_fp8_f32(v0.z * scale, v0.w * scale, w0, 1);
  int w1 = __builtin_amdgcn_cvt_pk_fp8_f32(v1.x * scale, v1.y * scale, 0, 0);
  w1     = __builtin_amdgcn_cvt_pk_fp8_f32(v1.z * scale, v1.w * scale, w1, 1);
  uint32_t* orow = (uint32_t*)(Xn + (size_t)row * DBYTES);
  orow[lane]      = (uint32_t)w0;
  orow[lane + 64] = (uint32_t)w1;
}

// ---- kernel 2: barrier-free strip GEMM, fused exp row/col sums -------------
// Each block: one 128-row A-strip at FULL depth (128 x 512 B = 64 KB LDS),
// staged once (16 global_load_lds per thread, ONE __syncthreads). Then sweep
// <=4 col-tiles x 4 K-iters; B-frags loaded global->register (L2-resident Xn),
// double-buffered across kk -> no barrier in the K-loop, vmcnt never drains
// to 0 (AITER-style). mfma_scale 16x16x128 f8f6f4, unit scales. A-frag LDS
// reads use the R2-verified XOR swizzle within each 128 B K-chunk.
// NO device-scope fences (R3 lesson: per-block L2 wb/inv -> 3x slowdown).
__global__ __launch_bounds__(256, 2) void gemm_exp_rowsum(const u8* __restrict__ Xn,
                                                          float* __restrict__ tsum) {
  __shared__ __align__(16) u8 sA[128 * 512];  // 64 KB

  // chunk decode: blockIdx.x -> (bi, c0): bi-group g has 4 rows x (g+1) chunks
  const int id = blockIdx.x;
  int g = (int)((sqrtf(1.0f + 2.0f * (float)id) - 1.0f) * 0.5f);
  while (2 * (g + 1) * (g + 2) <= id) ++g;
  while (2 * g * (g + 1) > id) --g;
  const int rem = id - 2 * g * (g + 1);
  const int bi  = 4 * g + rem / (g + 1);
  const int c0  = (rem % (g + 1)) * 4;          // first col-tile of this chunk
  const int ntiles = min(4, bi - c0 + 1);
  const int rowBase = bi * 128;

  const int t    = threadIdx.x;   // 0..255
  const int lane = t & 63;
  const int l15  = lane & 15;
  const int quad = lane >> 4;
  const int w    = t >> 6;        // 0..3
  const int wm   = w >> 1;        // 0..1: row offset wm*64
  const int wn   = w & 1;         // 0..1: col offset wn*64

  // ---- A-strip staging (once): granule l = t + i*256 of 4096 16B granules.
  // l -> row=l>>5, kk=(l>>3)&3, j=l&7 stored at slot j (global src j^(row&7)).
  // i increments -> row += 8 (row&7 unchanged) -> global += 8*512.
  {
    const int arow = t >> 5;
    const int akk  = (t >> 3) & 3;
    const int ajl  = (t & 7) ^ (arow & 7);
    const u8* gsrc = Xn + (size_t)(rowBase + arow) * DBYTES + akk * 128 + ajl * 16;
    u8* ldst = sA + t * 16;
#pragma unroll
    for (int i = 0; i < 16; i++)
      load16_to_lds(gsrc + (size_t)i * 4096, ldst + i * 4096);
  }

  i32x8_t bcur[4], bnxt[4];
  loadB(Xn, c0 * 128, wn, l15, quad, 0, bcur);  // in flight during A drain
  __syncthreads();  // the ONLY barrier: A-strip ready

  for (int ti = 0; ti < ntiles; ++ti) {
    const int colBase = (c0 + ti) * 128;
    const bool isDiag = (c0 + ti == bi);

    f32x4_t acc[4][4];
#pragma unroll
    for (int i = 0; i < 4; i++)
#pragma unroll
      for (int j = 0; j < 4; j++) acc[i][j] = {0.f, 0.f, 0.f, 0.f};

#pragma unroll
    for (int kk = 0; kk < 4; kk++) {
      // prefetch next B (next kk, or next tile's kk=0 -- flies over epilogue)
      if (kk < 3) {
        loadB(Xn, colBase, wn, l15, quad, kk + 1, bnxt);
      } else {
        const int nb = (ti + 1 < ntiles) ? colBase + 128 : colBase;
        loadB(Xn, nb, wn, l15, quad, 0, bnxt);
      }
      // A-frags from LDS (swizzled, conflict-free)
      i32x8_t a[4];
#pragma unroll
      for (int mi = 0; mi < 4; mi++) {
        const int row = wm * 64 + mi * 16 + l15;
        const int base = row * 512 + kk * 128;
        const int s0 = (((quad * 2) ^ (row & 7)) * 16);
        const int s1 = (((quad * 2 + 1) ^ (row & 7)) * 16);
        int4 lo = *(const int4*)&sA[base + s0];
        int4 hi = *(const int4*)&sA[base + s1];
        a[mi] = (i32x8_t){lo.x, lo.y, lo.z, lo.w, hi.x, hi.y, hi.z, hi.w};
      }
#pragma unroll
      for (int mi = 0; mi < 4; mi++)
#pragma unroll
        for (int ni = 0; ni < 4; ni++)
          acc[mi][ni] = __builtin_amdgcn_mfma_scale_f32_16x16x128_f8f6f4(
              a[mi], bcur[ni], acc[mi][ni], 0, 0, 0, 0x7F7F7F7Fu, 0, 0x7F7F7F7Fu);
#pragma unroll
      for (int ni = 0; ni < 4; ni++) bcur[ni] = bnxt[ni];
    }

    // epilogue: e = exp((c-1)/T). C/D layout: col = lane&15, row = quad*4+reg.
    if (isDiag) {
#pragma unroll
      for (int mi = 0; mi < 4; mi++) {
#pragma unroll
        for (int r = 0; r < 4; r++) {
          const int row = rowBase + wm * 64 + mi * 16 + quad * 4 + r;
          float rs = 0.0f;
#pragma unroll
          for (int ni = 0; ni < 4; ni++) {
            const int col = colBase + wn * 64 + ni * 16 + l15;
            const float e = __expf((acc[mi][ni][r] - 1.0f) * INV_T);
            rs += (row == col) ? 0.0f : e;
          }
          rs += __shfl_xor(rs, 1);
          rs += __shfl_xor(rs, 2);
          rs += __shfl_xor(rs, 4);
          rs += __shfl_xor(rs, 8);
          if (l15 == 0) atomicAdd(&tsum[row], rs);
        }
      }
    } else {
      float csum[4] = {0.f, 0.f, 0.f, 0.f};
#pragma unroll
      for (int mi = 0; mi < 4; mi++) {
#pragma unroll
        for (int r = 0; r < 4; r++) {
          const int row = rowBase + wm * 64 + mi * 16 + quad * 4 + r;
          float rs = 0.0f;
#pragma unroll
          for (int ni = 0; ni < 4; ni++) {
            const float e = __expf((acc[mi][ni][r] - 1.0f) * INV_T);
            rs += e;
            csum[ni] += e;
          }
          rs += __shfl_xor(rs, 1);
          rs += __shfl_xor(rs, 2);
          rs += __shfl_xor(rs, 4);
          rs += __shfl_xor(rs, 8);
          if (l15 == 0) atomicAdd(&tsum[row], rs);
        }
      }
#pragma unroll
      for (int ni = 0; ni < 4; ni++) {
        csum[ni] += __shfl_xor(csum[ni], 16);
        csum[ni] += __shfl_xor(csum[ni], 32);
        if (quad == 0) atomicAdd(&tsum[colBase + wn * 64 + ni * 16 + l15], csum[ni]);
      }
    }
  }
}

// ---- kernel 3: loss = mean_i log1p(t_i), 32 blocks + atomic accumulate -----
__global__ __launch_bounds__(256) void finalize_kernel(const float* __restrict__ tsum,
                                                       float* __restrict__ out) {
  const int i = blockIdx.x * 256 + threadIdx.x;
  float s = log1pf(tsum[i]);
#pragma unroll
  for (int m = 1; m < 64; m <<= 1) s += __shfl_xor(s, m);
  __shared__ float ws[4];
  if ((threadIdx.x & 63) == 0) ws[threadIdx.x >> 6] = s;
  __syncthreads();
  if (threadIdx.x == 0)
    atomicAdd(out, (ws[0] + ws[1] + ws[2] + ws[3]) * (1.0f / N_TOT));
}

// ---- launcher --------------------------------------------------------------
extern "C" void kernel_launch(void* const* d_in, const int* in_sizes, int n_in,
                              void* d_out, int out_size, void* d_ws, size_t ws_size,
                              hipStream_t stream) {
  const float* X = (const float*)d_in[0];
  float* out = (float*)d_out;

  float* tsum = (float*)d_ws;                       // 8192 fp32 = 32 KB
  u8* Xn = (u8*)d_ws + 65536;                       // 8192x512 fp8 = 4 MB

  normalize_kernel<<<N_TOT / 4, 256, 0, stream>>>(X, Xn, tsum, out);
  gemm_exp_rowsum<<<NCHUNK, 256, 0, stream>>>(Xn, tsum);
  finalize_kernel<<<N_TOT / 256, 256, 0, stream>>>(tsum, out);
}